// Round 8
// baseline (163.149 us; speedup 1.0000x reference)
//
#include <hip/hip_runtime.h>
#include <hip/hip_bf16.h>
#include <stdint.h>

typedef __hip_bfloat16 bf16;
typedef __attribute__((ext_vector_type(8))) short short8;   // 8 bf16 = 4 VGPRs (MFMA A/B frag)
typedef __attribute__((ext_vector_type(4))) float floatx4;  // MFMA C/D frag

#define MFMA_BF16(a, b, c) __builtin_amdgcn_mfma_f32_16x16x32_bf16((a), (b), (c), 0, 0, 0)

// Problem constants: B=2, N=2048, C=1024, H=8, D=128, half-window 128.
// qkv workspace layout: [b][n][3*C] with col = which*1024 + h*128 + d
// Vt layout: [b][h][d][n]  (PV B-frags contiguous in key)

// ---------------------------------------------------------------------------
// async global->LDS 16B copy: LDS dst is wave-uniform (lane i lands at
// dst + i*16 bytes); gsrc is per-lane (arbitrary gather). [m97/m104-verified]
// ---------------------------------------------------------------------------
__device__ __forceinline__ void gl_lds16(const bf16* gsrc, bf16* lds_dst)
{
    __builtin_amdgcn_global_load_lds(
        (const __attribute__((address_space(1))) uint32_t*)(uintptr_t)gsrc,
        (__attribute__((address_space(3))) uint32_t*)(uintptr_t)lds_dst,
        16, 0, 0);
}

// ---------------------------------------------------------------------------
// Dtype sniff: bf16 N(0,1) halfword[2i] has exponent in [100,140] ~always;
// fp32 low-mantissa halfwords hit that band ~16%.
// ---------------------------------------------------------------------------
__device__ __forceinline__ int sniff_bf16(const uint16_t* __restrict__ x)
{
    int cnt = 0;
#pragma unroll
    for (int i = 0; i < 64; ++i) {
        const int e = (x[2 * i] >> 7) & 0xFF;
        cnt += (e >= 100 && e <= 140) ? 1 : 0;
    }
    return (cnt >= 32) ? 1 : 0;
}

// ---------------------------------------------------------------------------
// One fused conversion kernel: x / w_qkv / w_proj -> bf16 (8 elems/thread),
// biases -> fp32. Grid = 4100 blocks x 256.
// ---------------------------------------------------------------------------
__global__ void __launch_bounds__(256)
cvt_all_kernel(const void* __restrict__ x, const void* __restrict__ wq,
               const void* __restrict__ wp, const void* __restrict__ bq,
               const void* __restrict__ bp,
               bf16* __restrict__ xb, bf16* __restrict__ wqb,
               bf16* __restrict__ wpb, float* __restrict__ bqf,
               float* __restrict__ bpf)
{
    __shared__ int sflag;
    if (threadIdx.x == 0) sflag = sniff_bf16((const uint16_t*)x);
    __syncthreads();
    const bool isbf = (sflag != 0);

    const int blk = blockIdx.x;
    if (blk < 4096) {
        const void* src; bf16* dst; int base;
        if (blk < 2048)      { src = x;  dst = xb;  base = blk << 11; }
        else if (blk < 3584) { src = wq; dst = wqb; base = (blk - 2048) << 11; }
        else                 { src = wp; dst = wpb; base = (blk - 3584) << 11; }
        const int i = base + (int)threadIdx.x * 8;
        if (isbf) {
            *(uint4*)(dst + i) = *(const uint4*)((const bf16*)src + i);
        } else {
            const float4 f0 = *(const float4*)((const float*)src + i);
            const float4 f1 = *(const float4*)((const float*)src + i + 4);
            bf16 o[8];
            o[0] = __float2bfloat16(f0.x); o[1] = __float2bfloat16(f0.y);
            o[2] = __float2bfloat16(f0.z); o[3] = __float2bfloat16(f0.w);
            o[4] = __float2bfloat16(f1.x); o[5] = __float2bfloat16(f1.y);
            o[6] = __float2bfloat16(f1.z); o[7] = __float2bfloat16(f1.w);
            *(uint4*)(dst + i) = *(uint4*)o;
        }
    } else {
        const void* src; float* dst; int base, n;
        if (blk < 4099) { src = bq; dst = bqf; base = (blk - 4096) * 1024; n = 3072; }
        else            { src = bp; dst = bpf; base = 0;                   n = 1024; }
        const int i0 = base + (int)threadIdx.x * 4;
#pragma unroll
        for (int k = 0; k < 4; ++k) {
            const int idx = i0 + k;
            if (idx < n)
                dst[idx] = isbf ? __bfloat162float(((const bf16*)src)[idx])
                                : ((const float*)src)[idx];
        }
    }
}

// ---------------------------------------------------------------------------
// GEMM: C[m,n] = sum_k A[m,k] * W[n,k] + bias[n]   (x @ W^T + b, W row-major)
// 128x128 tile, BK=32, DOUBLE-BUFFERED single-barrier pipeline:
//   stage(0); loop { barrier; stage(k+1 -> other buf); compute(k) }
// At each barrier only stage(k) is outstanding -> vmcnt(0) drains exactly
// what's needed (avoids the m131 trap); stage(k+1) latency overlaps
// compute(k). One barrier per iter. 32 KB LDS -> 3+ blocks/CU.
// ---------------------------------------------------------------------------
template <bool FUSE_VT, bool DYN_OUT>
__global__ void __launch_bounds__(256, 2)
gemm_bt_kernel(const bf16* __restrict__ A, const bf16* __restrict__ W,
               const float* __restrict__ bias, void* __restrict__ Cout,
               int M, int Nc, int K, bf16* __restrict__ Vt,
               const uint16_t* __restrict__ sniffsrc)
{
    __shared__ __align__(16) bf16 As[2][128][32];  // [buf][row][k] 16 KB
    __shared__ __align__(16) bf16 Bs[2][128][32];
    __shared__ int sflag;

    const int tid  = threadIdx.x;
    const int lane = tid & 63;
    const int wave = tid >> 6;
    const int quad = lane >> 4;
    const int l16  = lane & 15;
    const int wm   = (wave & 1) * 64;
    const int wn   = (wave >> 1) * 64;
    const int bm   = blockIdx.x * 128;
    const int bn   = blockIdx.y * 128;

    if (DYN_OUT && tid == 0) sflag = sniff_bf16(sniffsrc);

    // staging: chunk c = (wave*2+t)*64 + lane; row = c>>2, 16B col = c&3
    const int grow = wave * 32 + (lane >> 2);   // row for t=0 (t=1 adds 16)
    const int gcol = (lane & 3) * 8;            // element col within panel
    const bf16* Ag = A + (size_t)(bm + grow) * K + gcol;
    const bf16* Wg = W + (size_t)(bn + grow) * K + gcol;
    const int w0 = (wave * 2 + 0) * 512;
    const int w1 = (wave * 2 + 1) * 512;

    floatx4 acc[4][4];
#pragma unroll
    for (int i = 0; i < 4; ++i)
#pragma unroll
        for (int j = 0; j < 4; ++j)
#pragma unroll
            for (int r = 0; r < 4; ++r) acc[i][j][r] = 0.0f;

    auto stage = [&](int k0, int buf) {
        gl_lds16(Ag + k0,                  &As[buf][0][0] + w0);
        gl_lds16(Ag + (size_t)16 * K + k0, &As[buf][0][0] + w1);
        gl_lds16(Wg + k0,                  &Bs[buf][0][0] + w0);
        gl_lds16(Wg + (size_t)16 * K + k0, &Bs[buf][0][0] + w1);
    };

    stage(0, 0);
    const int niter = K >> 5;
    for (int it = 0; it < niter; ++it) {
        const int buf = it & 1;
        __syncthreads();                       // stage(it) complete; prev reads done
        if (it + 1 < niter) stage((it + 1) << 5, buf ^ 1);

        short8 af[4], bfr[4];
#pragma unroll
        for (int i = 0; i < 4; ++i)
            af[i] = *(const short8*)(&As[buf][wm + i * 16 + l16][quad * 8]);
#pragma unroll
        for (int j = 0; j < 4; ++j)
            bfr[j] = *(const short8*)(&Bs[buf][wn + j * 16 + l16][quad * 8]);
#pragma unroll
        for (int i = 0; i < 4; ++i)
#pragma unroll
            for (int j = 0; j < 4; ++j)
                acc[i][j] = MFMA_BF16(af[i], bfr[j], acc[i][j]);
    }

    const bool outbf = DYN_OUT ? (sflag != 0) : true;

    // epilogue: C/D layout row = quad*4+r, col = l16
#pragma unroll
    for (int i = 0; i < 4; ++i) {
#pragma unroll
        for (int j = 0; j < 4; ++j) {
            const int col = bn + wn + j * 16 + l16;
            const float bv = bias[col];
#pragma unroll
            for (int r = 0; r < 4; ++r) {
                const int row = bm + wm + i * 16 + quad * 4 + r;
                const float v = acc[i][j][r] + bv;
                const size_t idx = (size_t)row * Nc + col;
                if (!DYN_OUT || outbf) {
                    ((bf16*)Cout)[idx] = __float2bfloat16(v);
                } else {
                    ((float*)Cout)[idx] = v;
                }
                if (FUSE_VT) {
                    if (col >= 2048) {  // V columns -> transposed copy
                        const int hh = (col - 2048) >> 7;
                        const int dd = (col - 2048) & 127;
                        const int bb = row >> 11;     // M = 4096 = B*N
                        const int nn = row & 2047;
                        Vt[(((size_t)bb * 8 + hh) * 128 + dd) * 2048 + nn] =
                            __float2bfloat16(v);
                    }
                }
            }
        }
    }
}

// ---------------------------------------------------------------------------
// Banded attention v4: block = 4 waves / 64 queries; K/V staged into LDS in
// exact MFMA B-frag order, DOUBLE-BUFFERED with the single-barrier pipeline
// (stage chunk t+1 after barrier, before compute t). One barrier per 64-key
// chunk. Plds is wave-private (no dbuf; compiler orders LDS RAW/WAR within
// the wave). LDS = 64 + 9.2 KB -> 2 blocks/CU (= grid residency).
// Shift-free softmax (|s/32| tiny -> exp can't overflow; p/rowsum deferred).
// XCD swizzle: blockIdx%16 = b*8+h keeps each head's K/V on one XCD's L2.
// ---------------------------------------------------------------------------
__global__ void __launch_bounds__(256, 2)
attn_kernel(const bf16* __restrict__ qkv, const bf16* __restrict__ Vt,
            bf16* __restrict__ out)
{
    __shared__ __align__(16) bf16 Kl[2][16 * 512];   // 32 KB, frag-ordered
    __shared__ __align__(16) bf16 Vl[2][16 * 512];   // 32 KB, frag-ordered
    __shared__ __align__(16) bf16 Plds[4][16][72];   // 9.2 KB, wave-private P

    const int tid  = threadIdx.x;
    const int wave = tid >> 6;
    const int lane = tid & 63;
    const int quad = lane >> 4;
    const int l16  = lane & 15;

    const int hb = blockIdx.x & 15;      // b*8 + h  (XCD L2 locality)
    const int qb = blockIdx.x >> 4;      // 0..31, 64 queries per block
    const int h  = hb & 7;
    const int b  = hb >> 3;
    const int q0 = qb * 64 + wave * 16;  // this wave's 16 queries

    // Q A-frags: A[m=l16][k=quad*8+j], 4 d-chunks of 32
    short8 qf[4];
    {
        const bf16* Qbase = qkv + (size_t)(b * 2048 + q0 + l16) * 3072 + h * 128 + quad * 8;
#pragma unroll
        for (int d = 0; d < 4; ++d)
            qf[d] = *(const short8*)(Qbase + d * 32);
    }

    floatx4 Oacc[8];
#pragma unroll
    for (int dt = 0; dt < 8; ++dt)
#pragma unroll
        for (int r = 0; r < 4; ++r) Oacc[dt][r] = 0.0f;
    float psum[4] = {0.0f, 0.0f, 0.0f, 0.0f};

    // staging lane decomposition: sl = row-within-tile, sq = 16B col group
    const int sl = lane & 15;
    const int sq = lane >> 4;
    const bf16* Kbase = qkv + (size_t)b * 2048 * 3072 + 1024 + h * 128;  // +n*3072+d
    const bf16* Vtb   = Vt + (size_t)hb * 128 * 2048;                    // +d*2048+n

    int lo = qb * 64 - 127; if (lo < 0) lo = 0; lo &= ~63;
    int hi = qb * 64 + 63 + 127; if (hi > 2047) hi = 2047;
    const int nchunks = ((hi - lo) >> 6) + 1;

    // stage one 64-key chunk: K tiles tk=kt*4+dc (B-frag order), V tiles
    // tv=dt*2+ks; per wave 4 K-tiles + 4 V-tiles.
    auto stage = [&](int key0, int buf) {
#pragma unroll
        for (int i = 0; i < 4; ++i) {
            const int tk = wave * 4 + i;
            const int kt = tk >> 2, dc = tk & 3;
            gl_lds16(Kbase + (size_t)(key0 + kt * 16 + sl) * 3072 + dc * 32 + sq * 8,
                     &Kl[buf][0] + tk * 512);
        }
#pragma unroll
        for (int i = 0; i < 4; ++i) {
            const int tv = wave * 4 + i;
            const int dt = tv >> 1, ks = tv & 1;
            gl_lds16(Vtb + (size_t)(dt * 16 + sl) * 2048 + key0 + ks * 32 + sq * 8,
                     &Vl[buf][0] + tv * 512);
        }
    };

    stage(lo, 0);
    for (int t = 0; t < nchunks; ++t) {
        const int key0 = lo + t * 64;
        const int buf  = t & 1;
        __syncthreads();                      // stage(t) complete; prev reads done
        if (t + 1 < nchunks) stage(key0 + 64, buf ^ 1);

        // ---- S = Q K^T : 4 tiles of 16 keys ----
        floatx4 s[4];
#pragma unroll
        for (int kt = 0; kt < 4; ++kt) {
#pragma unroll
            for (int r = 0; r < 4; ++r) s[kt][r] = 0.0f;
#pragma unroll
            for (int dc = 0; dc < 4; ++dc) {
                short8 kf = *(const short8*)(&Kl[buf][0] + (kt * 4 + dc) * 512 + lane * 8);
                s[kt] = MFMA_BF16(qf[dc], kf, s[kt]);
            }
        }
        // ---- p = band ? exp(s/32) : 0 ; row-sum; store P to LDS ----
#pragma unroll
        for (int kt = 0; kt < 4; ++kt) {
#pragma unroll
            for (int r = 0; r < 4; ++r) {
                const int i = q0 + quad * 4 + r;
                const int j = key0 + kt * 16 + l16;
                const bool ok = (unsigned)(i - j + 127) < 255u;  // |i-j| < 128
                const float p = ok ? __expf(s[kt][r] * 0.03125f) : 0.0f;
                psum[r] += p;
                Plds[wave][quad * 4 + r][kt * 16 + l16] = __float2bfloat16(p);
            }
        }
        // ---- O += P V : P as A-frag (2 k-steps of 32 keys) ----
#pragma unroll
        for (int ks = 0; ks < 2; ++ks) {
            short8 pf = *(const short8*)(&Plds[wave][l16][ks * 32 + quad * 8]);
#pragma unroll
            for (int dt = 0; dt < 8; ++dt) {
                short8 vf = *(const short8*)(&Vl[buf][0] + (dt * 2 + ks) * 512 + lane * 8);
                Oacc[dt] = MFMA_BF16(pf, vf, Oacc[dt]);
            }
        }
    }

    // ---- deferred row-sum reduction across the 16 key-lanes ----
#pragma unroll
    for (int m = 1; m <= 8; m <<= 1)
#pragma unroll
        for (int r = 0; r < 4; ++r)
            psum[r] += __shfl_xor(psum[r], m, 64);

    // ---- write O / rowsum ----
#pragma unroll
    for (int r = 0; r < 4; ++r) {
        const float inv = 1.0f / psum[r];
        const int row = q0 + quad * 4 + r;
#pragma unroll
        for (int dt = 0; dt < 8; ++dt) {
            out[(size_t)(b * 2048 + row) * 1024 + h * 128 + dt * 16 + l16] =
                __float2bfloat16(Oacc[dt][r] * inv);
        }
    }
}

// ---------------------------------------------------------------------------
extern "C" void kernel_launch(void* const* d_in, const int* in_sizes, int n_in,
                              void* d_out, int out_size, void* d_ws, size_t ws_size,
                              hipStream_t stream)
{
    (void)in_sizes; (void)n_in; (void)out_size; (void)ws_size;

    const void* x      = d_in[0];  // (2, 2048, 1024)  fp32 (or bf16 — sniffed)
    const void* w_qkv  = d_in[1];  // (3072, 1024)
    const void* b_qkv  = d_in[2];  // (3072,)
    const void* w_proj = d_in[3];  // (1024, 1024)
    const void* b_proj = d_in[4];  // (1024,)

    char* ws = (char*)d_ws;
    bf16*  qkv      = (bf16*)(ws);                 // 25,165,824 B  [b][n][3C]
    bf16*  Vt       = (bf16*)(ws + 25165824);      //  8,388,608 B  [b][h][d][n]
    bf16*  attn_out = (bf16*)(ws + 33554432);      //  8,388,608 B  (b,n,c)
    bf16*  xb       = (bf16*)(ws + 41943040);      //  8,388,608 B
    bf16*  wqkvb    = (bf16*)(ws + 50331648);      //  6,291,456 B
    bf16*  wprojb   = (bf16*)(ws + 56623104);      //  2,097,152 B
    float* bqf      = (float*)(ws + 58720256);     //     12,288 B
    float* bpf      = (float*)(ws + 58732544);     //      4,096 B

    // 1) fused input normalization (sniff inlined per block)
    cvt_all_kernel<<<dim3(4100), dim3(256), 0, stream>>>(
        x, w_qkv, w_proj, b_qkv, b_proj, xb, wqkvb, wprojb, bqf, bpf);

    // 2) qkv = x @ w_qkv^T + b_qkv  (+ fused transposed-V write)
    gemm_bt_kernel<true, false><<<dim3(32, 24), dim3(256), 0, stream>>>(
        xb, wqkvb, bqf, qkv, 4096, 3072, 1024, Vt, (const uint16_t*)x);

    // 3) banded attention (dbuf LDS-staged K/V, XCD-swizzled)
    attn_kernel<<<dim3(512), dim3(256), 0, stream>>>(qkv, Vt, attn_out);

    // 4) out = attn @ w_proj^T + b_proj, output dtype per sniff
    gemm_bt_kernel<false, true><<<dim3(32, 8), dim3(256), 0, stream>>>(
        attn_out, wprojb, bpf, d_out, 4096, 1024, 1024, nullptr, (const uint16_t*)x);
}

// Round 9
// 159.840 us; speedup vs baseline: 1.0207x; 1.0207x over previous
//
#include <hip/hip_runtime.h>
#include <hip/hip_bf16.h>
#include <stdint.h>

typedef __hip_bfloat16 bf16;
typedef __attribute__((ext_vector_type(8))) short short8;   // 8 bf16 = 4 VGPRs (MFMA A/B frag)
typedef __attribute__((ext_vector_type(4))) float floatx4;  // MFMA C/D frag

#define MFMA_BF16(a, b, c) __builtin_amdgcn_mfma_f32_16x16x32_bf16((a), (b), (c), 0, 0, 0)

// Problem constants: B=2, N=2048, C=1024, H=8, D=128, half-window 128.
// qkv workspace layout: [b][n][3*C] with col = which*1024 + h*128 + d
// Vt layout: [b][h][d][n]  (PV B-frags contiguous in key)

// ---------------------------------------------------------------------------
// async global->LDS 16B copy: LDS dst is wave-uniform (lane i lands at
// dst + i*16 bytes); gsrc is per-lane (arbitrary gather). [m97/m104-verified]
// ---------------------------------------------------------------------------
__device__ __forceinline__ void gl_lds16(const bf16* gsrc, bf16* lds_dst)
{
    __builtin_amdgcn_global_load_lds(
        (const __attribute__((address_space(1))) uint32_t*)(uintptr_t)gsrc,
        (__attribute__((address_space(3))) uint32_t*)(uintptr_t)lds_dst,
        16, 0, 0);
}

// ---------------------------------------------------------------------------
// Dtype sniff: bf16 N(0,1) halfword[2i] has exponent in [100,140] ~always;
// fp32 low-mantissa halfwords hit that band ~16%.
// ---------------------------------------------------------------------------
__device__ __forceinline__ int sniff_bf16(const uint16_t* __restrict__ x)
{
    int cnt = 0;
#pragma unroll
    for (int i = 0; i < 64; ++i) {
        const int e = (x[2 * i] >> 7) & 0xFF;
        cnt += (e >= 100 && e <= 140) ? 1 : 0;
    }
    return (cnt >= 32) ? 1 : 0;
}

// ---------------------------------------------------------------------------
// One fused conversion kernel: x / w_qkv / w_proj -> bf16 (8 elems/thread),
// biases -> fp32. Grid = 4100 blocks x 256.
// ---------------------------------------------------------------------------
__global__ void __launch_bounds__(256)
cvt_all_kernel(const void* __restrict__ x, const void* __restrict__ wq,
               const void* __restrict__ wp, const void* __restrict__ bq,
               const void* __restrict__ bp,
               bf16* __restrict__ xb, bf16* __restrict__ wqb,
               bf16* __restrict__ wpb, float* __restrict__ bqf,
               float* __restrict__ bpf)
{
    __shared__ int sflag;
    if (threadIdx.x == 0) sflag = sniff_bf16((const uint16_t*)x);
    __syncthreads();
    const bool isbf = (sflag != 0);

    const int blk = blockIdx.x;
    if (blk < 4096) {
        const void* src; bf16* dst; int base;
        if (blk < 2048)      { src = x;  dst = xb;  base = blk << 11; }
        else if (blk < 3584) { src = wq; dst = wqb; base = (blk - 2048) << 11; }
        else                 { src = wp; dst = wpb; base = (blk - 3584) << 11; }
        const int i = base + (int)threadIdx.x * 8;
        if (isbf) {
            *(uint4*)(dst + i) = *(const uint4*)((const bf16*)src + i);
        } else {
            const float4 f0 = *(const float4*)((const float*)src + i);
            const float4 f1 = *(const float4*)((const float*)src + i + 4);
            bf16 o[8];
            o[0] = __float2bfloat16(f0.x); o[1] = __float2bfloat16(f0.y);
            o[2] = __float2bfloat16(f0.z); o[3] = __float2bfloat16(f0.w);
            o[4] = __float2bfloat16(f1.x); o[5] = __float2bfloat16(f1.y);
            o[6] = __float2bfloat16(f1.z); o[7] = __float2bfloat16(f1.w);
            *(uint4*)(dst + i) = *(uint4*)o;
        }
    } else {
        const void* src; float* dst; int base, n;
        if (blk < 4099) { src = bq; dst = bqf; base = (blk - 4096) * 1024; n = 3072; }
        else            { src = bp; dst = bpf; base = 0;                   n = 1024; }
        const int i0 = base + (int)threadIdx.x * 4;
#pragma unroll
        for (int k = 0; k < 4; ++k) {
            const int idx = i0 + k;
            if (idx < n)
                dst[idx] = isbf ? __bfloat162float(((const bf16*)src)[idx])
                                : ((const float*)src)[idx];
        }
    }
}

// ---------------------------------------------------------------------------
// GEMM: C[m,n] = sum_k A[m,k] * W[n,k] + bias[n]   (x @ W^T + b, W row-major)
// 128x128 tile, BK=32 dbuf single-barrier pipeline, *** 8 waves (512 thr) ***
// in a 2x4 grid (wave tile 64x32, acc 4x2 tiles = 32 VGPRs). Rationale: the
// 4-wave version measured MfmaUtil 22 / VALUBusy 12 / Occ 22 -> latency-bound
// with ~8-12 waves/CU. 512-thr blocks at grid 768 give exactly 3 blocks/CU
// (1536 thr, 96 KB LDS, ~76 regs/wave -> 6 waves/SIMD) = ~24 waves/CU.
// ---------------------------------------------------------------------------
template <bool FUSE_VT, bool DYN_OUT>
__global__ void __launch_bounds__(512, 6)
gemm_bt_kernel(const bf16* __restrict__ A, const bf16* __restrict__ W,
               const float* __restrict__ bias, void* __restrict__ Cout,
               int M, int Nc, int K, bf16* __restrict__ Vt,
               const uint16_t* __restrict__ sniffsrc)
{
    __shared__ __align__(16) bf16 As[2][128][32];  // [buf][row][k] 16 KB
    __shared__ __align__(16) bf16 Bs[2][128][32];
    __shared__ int sflag;

    const int tid  = threadIdx.x;
    const int lane = tid & 63;
    const int wave = tid >> 6;          // 0..7
    const int quad = lane >> 4;
    const int l16  = lane & 15;
    const int wm   = (wave & 1) * 64;   // 2 row-groups
    const int wn   = (wave >> 1) * 32;  // 4 col-groups
    const int bm   = blockIdx.x * 128;
    const int bn   = blockIdx.y * 128;

    if (DYN_OUT && tid == 0) sflag = sniff_bf16(sniffsrc);

    // staging: wave w moves chunk w of A and chunk w of B (1 KB each).
    // chunk w = rows w*16 + (lane>>2), 16B col (lane&3).
    const int grow = wave * 16 + (lane >> 2);
    const int gcol = (lane & 3) * 8;
    const bf16* Ag = A + (size_t)(bm + grow) * K + gcol;
    const bf16* Wg = W + (size_t)(bn + grow) * K + gcol;
    const int woff = wave * 512;        // chunk w -> elems [w*512, w*512+512)

    floatx4 acc[4][2];
#pragma unroll
    for (int i = 0; i < 4; ++i)
#pragma unroll
        for (int j = 0; j < 2; ++j)
#pragma unroll
            for (int r = 0; r < 4; ++r) acc[i][j][r] = 0.0f;

    auto stage = [&](int k0, int buf) {
        gl_lds16(Ag + k0, &As[buf][0][0] + woff);
        gl_lds16(Wg + k0, &Bs[buf][0][0] + woff);
    };

    stage(0, 0);
    const int niter = K >> 5;
    for (int it = 0; it < niter; ++it) {
        const int buf = it & 1;
        __syncthreads();                       // stage(it) complete; prev reads done
        if (it + 1 < niter) stage((it + 1) << 5, buf ^ 1);

        short8 af[4], bfr[2];
#pragma unroll
        for (int i = 0; i < 4; ++i)
            af[i] = *(const short8*)(&As[buf][wm + i * 16 + l16][quad * 8]);
#pragma unroll
        for (int j = 0; j < 2; ++j)
            bfr[j] = *(const short8*)(&Bs[buf][wn + j * 16 + l16][quad * 8]);
#pragma unroll
        for (int i = 0; i < 4; ++i)
#pragma unroll
            for (int j = 0; j < 2; ++j)
                acc[i][j] = MFMA_BF16(af[i], bfr[j], acc[i][j]);
    }

    const bool outbf = DYN_OUT ? (sflag != 0) : true;

    // epilogue: C/D layout row = quad*4+r, col = l16
#pragma unroll
    for (int i = 0; i < 4; ++i) {
#pragma unroll
        for (int j = 0; j < 2; ++j) {
            const int col = bn + wn + j * 16 + l16;
            const float bv = bias[col];
#pragma unroll
            for (int r = 0; r < 4; ++r) {
                const int row = bm + wm + i * 16 + quad * 4 + r;
                const float v = acc[i][j][r] + bv;
                const size_t idx = (size_t)row * Nc + col;
                if (!DYN_OUT || outbf) {
                    ((bf16*)Cout)[idx] = __float2bfloat16(v);
                } else {
                    ((float*)Cout)[idx] = v;
                }
                if (FUSE_VT) {
                    if (col >= 2048) {  // V columns -> transposed copy
                        const int hh = (col - 2048) >> 7;
                        const int dd = (col - 2048) & 127;
                        const int bb = row >> 11;     // M = 4096 = B*N
                        const int nn = row & 2047;
                        Vt[(((size_t)bb * 8 + hh) * 128 + dd) * 2048 + nn] =
                            __float2bfloat16(v);
                    }
                }
            }
        }
    }
}

// ---------------------------------------------------------------------------
// Banded attention v4 (unchanged from round 8): block = 4 waves / 64 queries;
// K/V staged in MFMA B-frag order, dbuf single-barrier pipeline; wave-private
// Plds; shift-free softmax; XCD swizzle (blockIdx%16 = b*8+h).
// ---------------------------------------------------------------------------
__global__ void __launch_bounds__(256, 2)
attn_kernel(const bf16* __restrict__ qkv, const bf16* __restrict__ Vt,
            bf16* __restrict__ out)
{
    __shared__ __align__(16) bf16 Kl[2][16 * 512];   // 32 KB, frag-ordered
    __shared__ __align__(16) bf16 Vl[2][16 * 512];   // 32 KB, frag-ordered
    __shared__ __align__(16) bf16 Plds[4][16][72];   // 9.2 KB, wave-private P

    const int tid  = threadIdx.x;
    const int wave = tid >> 6;
    const int lane = tid & 63;
    const int quad = lane >> 4;
    const int l16  = lane & 15;

    const int hb = blockIdx.x & 15;      // b*8 + h  (XCD L2 locality)
    const int qb = blockIdx.x >> 4;      // 0..31, 64 queries per block
    const int h  = hb & 7;
    const int b  = hb >> 3;
    const int q0 = qb * 64 + wave * 16;  // this wave's 16 queries

    short8 qf[4];
    {
        const bf16* Qbase = qkv + (size_t)(b * 2048 + q0 + l16) * 3072 + h * 128 + quad * 8;
#pragma unroll
        for (int d = 0; d < 4; ++d)
            qf[d] = *(const short8*)(Qbase + d * 32);
    }

    floatx4 Oacc[8];
#pragma unroll
    for (int dt = 0; dt < 8; ++dt)
#pragma unroll
        for (int r = 0; r < 4; ++r) Oacc[dt][r] = 0.0f;
    float psum[4] = {0.0f, 0.0f, 0.0f, 0.0f};

    const int sl = lane & 15;
    const int sq = lane >> 4;
    const bf16* Kbase = qkv + (size_t)b * 2048 * 3072 + 1024 + h * 128;  // +n*3072+d
    const bf16* Vtb   = Vt + (size_t)hb * 128 * 2048;                    // +d*2048+n

    int lo = qb * 64 - 127; if (lo < 0) lo = 0; lo &= ~63;
    int hi = qb * 64 + 63 + 127; if (hi > 2047) hi = 2047;
    const int nchunks = ((hi - lo) >> 6) + 1;

    auto stage = [&](int key0, int buf) {
#pragma unroll
        for (int i = 0; i < 4; ++i) {
            const int tk = wave * 4 + i;
            const int kt = tk >> 2, dc = tk & 3;
            gl_lds16(Kbase + (size_t)(key0 + kt * 16 + sl) * 3072 + dc * 32 + sq * 8,
                     &Kl[buf][0] + tk * 512);
        }
#pragma unroll
        for (int i = 0; i < 4; ++i) {
            const int tv = wave * 4 + i;
            const int dt = tv >> 1, ks = tv & 1;
            gl_lds16(Vtb + (size_t)(dt * 16 + sl) * 2048 + key0 + ks * 32 + sq * 8,
                     &Vl[buf][0] + tv * 512);
        }
    };

    stage(lo, 0);
    for (int t = 0; t < nchunks; ++t) {
        const int key0 = lo + t * 64;
        const int buf  = t & 1;
        __syncthreads();                      // stage(t) complete; prev reads done
        if (t + 1 < nchunks) stage(key0 + 64, buf ^ 1);

        floatx4 s[4];
#pragma unroll
        for (int kt = 0; kt < 4; ++kt) {
#pragma unroll
            for (int r = 0; r < 4; ++r) s[kt][r] = 0.0f;
#pragma unroll
            for (int dc = 0; dc < 4; ++dc) {
                short8 kf = *(const short8*)(&Kl[buf][0] + (kt * 4 + dc) * 512 + lane * 8);
                s[kt] = MFMA_BF16(qf[dc], kf, s[kt]);
            }
        }
#pragma unroll
        for (int kt = 0; kt < 4; ++kt) {
#pragma unroll
            for (int r = 0; r < 4; ++r) {
                const int i = q0 + quad * 4 + r;
                const int j = key0 + kt * 16 + l16;
                const bool ok = (unsigned)(i - j + 127) < 255u;  // |i-j| < 128
                const float p = ok ? __expf(s[kt][r] * 0.03125f) : 0.0f;
                psum[r] += p;
                Plds[wave][quad * 4 + r][kt * 16 + l16] = __float2bfloat16(p);
            }
        }
#pragma unroll
        for (int ks = 0; ks < 2; ++ks) {
            short8 pf = *(const short8*)(&Plds[wave][l16][ks * 32 + quad * 8]);
#pragma unroll
            for (int dt = 0; dt < 8; ++dt) {
                short8 vf = *(const short8*)(&Vl[buf][0] + (dt * 2 + ks) * 512 + lane * 8);
                Oacc[dt] = MFMA_BF16(pf, vf, Oacc[dt]);
            }
        }
    }

#pragma unroll
    for (int m = 1; m <= 8; m <<= 1)
#pragma unroll
        for (int r = 0; r < 4; ++r)
            psum[r] += __shfl_xor(psum[r], m, 64);

#pragma unroll
    for (int r = 0; r < 4; ++r) {
        const float inv = 1.0f / psum[r];
        const int row = q0 + quad * 4 + r;
#pragma unroll
        for (int dt = 0; dt < 8; ++dt) {
            out[(size_t)(b * 2048 + row) * 1024 + h * 128 + dt * 16 + l16] =
                __float2bfloat16(Oacc[dt][r] * inv);
        }
    }
}

// ---------------------------------------------------------------------------
extern "C" void kernel_launch(void* const* d_in, const int* in_sizes, int n_in,
                              void* d_out, int out_size, void* d_ws, size_t ws_size,
                              hipStream_t stream)
{
    (void)in_sizes; (void)n_in; (void)out_size; (void)ws_size;

    const void* x      = d_in[0];  // (2, 2048, 1024)  fp32 (or bf16 — sniffed)
    const void* w_qkv  = d_in[1];  // (3072, 1024)
    const void* b_qkv  = d_in[2];  // (3072,)
    const void* w_proj = d_in[3];  // (1024, 1024)
    const void* b_proj = d_in[4];  // (1024,)

    char* ws = (char*)d_ws;
    bf16*  qkv      = (bf16*)(ws);                 // 25,165,824 B  [b][n][3C]
    bf16*  Vt       = (bf16*)(ws + 25165824);      //  8,388,608 B  [b][h][d][n]
    bf16*  attn_out = (bf16*)(ws + 33554432);      //  8,388,608 B  (b,n,c)
    bf16*  xb       = (bf16*)(ws + 41943040);      //  8,388,608 B
    bf16*  wqkvb    = (bf16*)(ws + 50331648);      //  6,291,456 B
    bf16*  wprojb   = (bf16*)(ws + 56623104);      //  2,097,152 B
    float* bqf      = (float*)(ws + 58720256);     //     12,288 B
    float* bpf      = (float*)(ws + 58732544);     //      4,096 B

    // 1) fused input normalization (sniff inlined per block)
    cvt_all_kernel<<<dim3(4100), dim3(256), 0, stream>>>(
        x, w_qkv, w_proj, b_qkv, b_proj, xb, wqkvb, wprojb, bqf, bpf);

    // 2) qkv = x @ w_qkv^T + b_qkv  (+ fused transposed-V write), 8-wave blocks
    gemm_bt_kernel<true, false><<<dim3(32, 24), dim3(512), 0, stream>>>(
        xb, wqkvb, bqf, qkv, 4096, 3072, 1024, Vt, (const uint16_t*)x);

    // 3) banded attention (dbuf LDS-staged K/V, XCD-swizzled)
    attn_kernel<<<dim3(512), dim3(256), 0, stream>>>(qkv, Vt, attn_out);

    // 4) out = attn @ w_proj^T + b_proj, output dtype per sniff, 8-wave blocks
    gemm_bt_kernel<false, true><<<dim3(32, 8), dim3(512), 0, stream>>>(
        attn_out, wprojb, bpf, d_out, 4096, 1024, 1024, nullptr, (const uint16_t*)x);
}